// Round 1
// baseline (1156.822 us; speedup 1.0000x reference)
//
#include <hip/hip_runtime.h>
#include <math.h>

#define BATCH 64
#define NTOK  729
#define DIM   64
#define NROWS 46656   // BATCH*NTOK

// ---------------------------------------------------------------------------
// Direct 3x3 SAME conv, NCHW, 27x27 spatial. Input-side BN+ReLU optionally
// fused via scsh = [scale[Cin] | shift[Cin]] (v' = max(v*sc+sh, 0)).
// Output written to partial buffer [slab][B][Cout][729].
// Block: 256 threads; 243 active compute threads = 27 rows x 9 x-triples.
// ---------------------------------------------------------------------------
template<int CIN_CHUNK, int TC>
__global__ __launch_bounds__(256) void conv3x3_slab(
    const float* __restrict__ in, const float* __restrict__ wgt,
    const float* __restrict__ scsh, float* __restrict__ outp,
    int Cin, int Cout, int cinPerSlab, int nslab)
{
  int groups = Cout / TC;
  int blocksPerB = groups * nslab;
  int b = blockIdx.x / blocksPerB;
  int rr = blockIdx.x % blocksPerB;
  int g = rr / nslab;
  int slab = rr % nslab;
  int c_begin = slab * cinPerSlab;
  int c_end = c_begin + cinPerSlab; if (c_end > Cin) c_end = Cin;

  __shared__ float s_in[CIN_CHUNK * 841];   // padded 29x29 per channel
  __shared__ float s_w[TC * CIN_CHUNK * 9];
  __shared__ float s_sc[CIN_CHUNK];
  __shared__ float s_sh[CIN_CHUNK];

  const int tid = threadIdx.x;
  const bool active = tid < 243;
  const int py = tid / 9;
  const int px3 = (tid % 9) * 3;

  float acc[TC][3];
  #pragma unroll
  for (int t = 0; t < TC; ++t) { acc[t][0]=0.f; acc[t][1]=0.f; acc[t][2]=0.f; }

  for (int c0 = c_begin; c0 < c_end; c0 += CIN_CHUNK) {
    int ccn = c_end - c0; if (ccn > CIN_CHUNK) ccn = CIN_CHUNK;
    if (scsh != nullptr && tid < ccn) {
      s_sc[tid] = scsh[c0 + tid];
      s_sh[tid] = scsh[Cin + c0 + tid];
    }
    __syncthreads();   // also protects s_in from previous iteration's compute
    // stage input chunk (zero-padded 29x29), BN+ReLU fused if scsh
    for (int i = tid; i < ccn * 841; i += 256) {
      int cc = i / 841; int r2 = i - cc*841; int y = r2 / 29; int x2 = r2 - y*29;
      float v = 0.f;
      if (y >= 1 && y <= 27 && x2 >= 1 && x2 <= 27) {
        v = in[((size_t)b * Cin + (c0+cc)) * 729 + (y-1)*27 + (x2-1)];
        if (scsh != nullptr) v = fmaxf(fmaf(v, s_sc[cc], s_sh[cc]), 0.f);
      }
      s_in[i] = v;
    }
    for (int i = tid; i < TC * ccn * 9; i += 256) {
      int t = i / (ccn*9); int r2 = i - t*ccn*9; int cc = r2 / 9; int k = r2 - cc*9;
      s_w[(t*CIN_CHUNK + cc)*9 + k] = wgt[((size_t)(g*TC + t) * Cin + (c0+cc)) * 9 + k];
    }
    __syncthreads();
    if (active) {
      for (int cc = 0; cc < ccn; ++cc) {
        const float* bp = &s_in[cc*841 + py*29 + px3];
        float v00=bp[0],  v01=bp[1],  v02=bp[2],  v03=bp[3],  v04=bp[4];
        float v10=bp[29], v11=bp[30], v12=bp[31], v13=bp[32], v14=bp[33];
        float v20=bp[58], v21=bp[59], v22=bp[60], v23=bp[61], v24=bp[62];
        #pragma unroll
        for (int t = 0; t < TC; ++t) {
          const float* wp = &s_w[(t*CIN_CHUNK + cc)*9];
          float w0=wp[0],w1=wp[1],w2=wp[2],w3=wp[3],w4=wp[4],w5=wp[5],w6=wp[6],w7=wp[7],w8=wp[8];
          acc[t][0] += w0*v00+w1*v01+w2*v02 + w3*v10+w4*v11+w5*v12 + w6*v20+w7*v21+w8*v22;
          acc[t][1] += w0*v01+w1*v02+w2*v03 + w3*v11+w4*v12+w5*v13 + w6*v21+w7*v22+w8*v23;
          acc[t][2] += w0*v02+w1*v03+w2*v04 + w3*v12+w4*v13+w5*v14 + w6*v22+w7*v23+w8*v24;
        }
      }
    }
  }
  if (active) {
    #pragma unroll
    for (int t = 0; t < TC; ++t) {
      size_t base = (((size_t)slab*BATCH + b)*Cout + (g*TC + t))*729 + py*27 + px3;
      outp[base+0]=acc[t][0]; outp[base+1]=acc[t][1]; outp[base+2]=acc[t][2];
    }
  }
}

// ---------------------------------------------------------------------------
// Sum conv partials + bias -> out; accumulate per-channel sum/sumsq (BN stats)
// via double atomics. Block per (b, c).
// ---------------------------------------------------------------------------
__global__ __launch_bounds__(256) void conv_reduce_stats(
    const float* __restrict__ part, const float* __restrict__ bias,
    float* __restrict__ outp, double* __restrict__ stats, int C, int nslab)
{
  int b = blockIdx.x / C;
  int c = blockIdx.x % C;
  size_t slabStride = (size_t)BATCH * C * 729;
  size_t base = ((size_t)b * C + c) * 729;
  float bv = bias[c];
  float bsum = 0.f, bsq = 0.f;
  for (int e = threadIdx.x; e < 729; e += 256) {
    float v = bv;
    for (int s = 0; s < nslab; ++s) v += part[s*slabStride + base + e];
    outp[base + e] = v;
    bsum += v; bsq += v*v;
  }
  #pragma unroll
  for (int off = 32; off > 0; off >>= 1) {
    bsum += __shfl_down(bsum, off);
    bsq  += __shfl_down(bsq, off);
  }
  __shared__ float rs[4], rq[4];
  int wid = threadIdx.x >> 6;
  if ((threadIdx.x & 63) == 0) { rs[wid] = bsum; rq[wid] = bsq; }
  __syncthreads();
  if (threadIdx.x == 0) {
    float s1 = rs[0]+rs[1]+rs[2]+rs[3];
    float q1 = rq[0]+rq[1]+rq[2]+rq[3];
    atomicAdd(&stats[c], (double)s1);
    atomicAdd(&stats[C + c], (double)q1);
  }
}

// (sum, sumsq) + gamma/beta -> (scale, shift)
__global__ void bn_finalize(const double* __restrict__ stats,
                            const float* __restrict__ gamma, const float* __restrict__ beta,
                            float* __restrict__ scsh, int C, float invCount)
{
  int c = threadIdx.x + blockIdx.x * blockDim.x; if (c >= C) return;
  double mu = stats[c] * (double)invCount;
  double var = stats[C + c] * (double)invCount - mu * mu;
  float rstd = (float)(1.0 / sqrt(var + 1e-5));
  float sc = gamma[c] * rstd;
  scsh[c] = sc;
  scsh[C + c] = beta[c] - (float)mu * sc;
}

// ---------------------------------------------------------------------------
// BN+ReLU conv3 output and transpose [B,64,729] -> t [B,729,64]; also xx[b,n].
// Block per (b, 64-wide n tile).
// ---------------------------------------------------------------------------
__global__ __launch_bounds__(256) void bn_transpose_xx(
    const float* __restrict__ c3, const float* __restrict__ scsh,
    float* __restrict__ t, float* __restrict__ xx)
{
  int b = blockIdx.x / 12, nt = blockIdx.x % 12, n0 = nt * 64;
  __shared__ float s[64 * 65];
  for (int i = threadIdx.x; i < 4096; i += 256) {
    int d = i >> 6, j = i & 63; int n = n0 + j;
    float v = 0.f;
    if (n < 729) {
      v = c3[((size_t)b * 64 + d) * 729 + n];
      v = fmaxf(fmaf(v, scsh[d], scsh[64 + d]), 0.f);
    }
    s[d * 65 + j] = v;
  }
  __syncthreads();
  for (int i = threadIdx.x; i < 4096; i += 256) {
    int j = i >> 6, d = i & 63; int n = n0 + j;
    if (n < 729) t[((size_t)b * 729 + n) * 64 + d] = s[d * 65 + j];
  }
  if (threadIdx.x < 64) {
    int j = threadIdx.x; int n = n0 + j;
    if (n < 729) {
      float sm = 0.f;
      #pragma unroll
      for (int d = 0; d < 64; ++d) { float v = s[d * 65 + j]; sm += v * v; }
      xx[b * 729 + n] = sm;
    }
  }
}

// ---------------------------------------------------------------------------
// hs = t @ w_self, hw = t @ w_nb.  Block per (b, 64-n tile), 16x16 thread grid,
// 4x4 register tile per thread per matrix.
// ---------------------------------------------------------------------------
__global__ __launch_bounds__(256) void gemm_selfnb(
    const float* __restrict__ t, const float* __restrict__ wself,
    const float* __restrict__ wnb, float* __restrict__ hs, float* __restrict__ hw)
{
  int b = blockIdx.x / 12, nt = blockIdx.x % 12, n0 = nt * 64;
  __shared__ float s_t[64 * 65], s_a[64 * 65], s_b[64 * 65];
  for (int i = threadIdx.x; i < 4096; i += 256) {
    int n = i >> 6, d = i & 63;
    s_t[n * 65 + d] = (n0 + n < 729) ? t[((size_t)b * 729 + n0 + n) * 64 + d] : 0.f;
    s_a[n * 65 + d] = wself[i];
    s_b[n * 65 + d] = wnb[i];
  }
  __syncthreads();
  int ty = threadIdx.x >> 4, tx = threadIdx.x & 15;
  float acc0[4][4], acc1[4][4];
  #pragma unroll
  for (int i = 0; i < 4; ++i)
    #pragma unroll
    for (int j = 0; j < 4; ++j) { acc0[i][j] = 0.f; acc1[i][j] = 0.f; }
  #pragma unroll 4
  for (int d = 0; d < 64; ++d) {
    float av[4], b1v[4], b2v[4];
    #pragma unroll
    for (int i = 0; i < 4; ++i) av[i] = s_t[(4*ty + i) * 65 + d];
    #pragma unroll
    for (int j = 0; j < 4; ++j) { b1v[j] = s_a[d * 65 + 4*tx + j]; b2v[j] = s_b[d * 65 + 4*tx + j]; }
    #pragma unroll
    for (int i = 0; i < 4; ++i)
      #pragma unroll
      for (int j = 0; j < 4; ++j) { acc0[i][j] += av[i]*b1v[j]; acc1[i][j] += av[i]*b2v[j]; }
  }
  #pragma unroll
  for (int i = 0; i < 4; ++i) {
    int n = n0 + 4*ty + i;
    if (n < 729) {
      #pragma unroll
      for (int j = 0; j < 4; ++j) {
        size_t o = ((size_t)b * 729 + n) * 64 + 4*tx + j;
        hs[o] = acc0[i][j];
        hw[o] = acc1[i][j];
      }
    }
  }
}

// ---------------------------------------------------------------------------
// kNN: block per (b, 64-n tile). Tiled 64x64 score GEMM into LDS, fused
// streaming top-8 per row ranked by (xx[m] - 2*dot), (val,idx) lexicographic.
// Self excluded. Output: 8 neighbor indices (local to b) per row.
// ---------------------------------------------------------------------------
__global__ __launch_bounds__(256) void dist_topk(
    const float* __restrict__ t, const float* __restrict__ xx, int* __restrict__ nbr)
{
  int b = blockIdx.x / 12, nt = blockIdx.x % 12, n0 = nt * 64;
  __shared__ float s_n[64 * 65];
  __shared__ float s_m[64 * 65];
  __shared__ float s_S[64 * 65];

  float kv[8]; int ki[8];
  #pragma unroll
  for (int i = 0; i < 8; ++i) { kv[i] = 3.0e38f; ki[i] = 0x7fffffff; }

  for (int i = threadIdx.x; i < 4096; i += 256) {
    int n = i >> 6, d = i & 63;
    s_n[n * 65 + d] = (n0 + n < 729) ? t[((size_t)b * 729 + n0 + n) * 64 + d] : 0.f;
  }
  int ty = threadIdx.x >> 4, tx = threadIdx.x & 15;
  int r = threadIdx.x & 63, q = threadIdx.x >> 6;
  int n_self = n0 + r;

  for (int mt = 0; mt < 12; ++mt) {
    int m0 = mt * 64;
    __syncthreads();   // protect s_m/s_S from previous iteration's readers
    for (int i = threadIdx.x; i < 4096; i += 256) {
      int m = i >> 6, d = i & 63;
      s_m[m * 65 + d] = (m0 + m < 729) ? t[((size_t)b * 729 + m0 + m) * 64 + d] : 0.f;
    }
    __syncthreads();
    float acc[4][4];
    #pragma unroll
    for (int i = 0; i < 4; ++i)
      #pragma unroll
      for (int j = 0; j < 4; ++j) acc[i][j] = 0.f;
    #pragma unroll 4
    for (int d = 0; d < 64; ++d) {
      float av[4], bv[4];
      #pragma unroll
      for (int i = 0; i < 4; ++i) av[i] = s_n[(4*ty + i) * 65 + d];
      #pragma unroll
      for (int j = 0; j < 4; ++j) bv[j] = s_m[(4*tx + j) * 65 + d];
      #pragma unroll
      for (int i = 0; i < 4; ++i)
        #pragma unroll
        for (int j = 0; j < 4; ++j) acc[i][j] += av[i] * bv[j];
    }
    #pragma unroll
    for (int j = 0; j < 4; ++j) {
      int m = m0 + 4*tx + j;
      float xm = (m < 729) ? xx[b * 729 + m] : 3.0e38f;
      #pragma unroll
      for (int i = 0; i < 4; ++i)
        s_S[(4*ty + i) * 65 + 4*tx + j] = fmaf(-2.f, acc[i][j], xm);
    }
    __syncthreads();
    // scan: thread (r, q) handles columns q*16 .. q*16+15 of row r
    for (int i2 = 0; i2 < 16; ++i2) {
      int m = m0 + q * 16 + i2;
      float sv = s_S[r * 65 + q * 16 + i2];
      bool valid = (m < 729) && (m != n_self);
      bool lt = valid && ((sv < kv[7]) || (sv == kv[7] && m < ki[7]));
      if (lt) {
        float cv = sv; int ci = m;
        #pragma unroll
        for (int ii = 0; ii < 8; ++ii) {
          bool less = (cv < kv[ii]) || (cv == kv[ii] && ci < ki[ii]);
          float tv = less ? kv[ii] : cv; int ti = less ? ki[ii] : ci;
          kv[ii] = less ? cv : kv[ii]; ki[ii] = less ? ci : ki[ii];
          cv = tv; ci = ti;
        }
      }
    }
  }
  __syncthreads();
  // merge the 4 per-thread lists per row (reuse s_m/s_n as val/idx [64][33])
  float* mv = s_m;
  int*   mi = (int*)s_n;
  #pragma unroll
  for (int i2 = 0; i2 < 8; ++i2) { mv[r*33 + q*8 + i2] = kv[i2]; mi[r*33 + q*8 + i2] = ki[i2]; }
  __syncthreads();
  if (threadIdx.x < 64) {
    int n = n0 + threadIdx.x;
    if (n < 729) {
      int rb = threadIdx.x * 33;
      int p0 = 0, p1 = 0, p2 = 0, p3 = 0;
      int* op = &nbr[((size_t)b * 729 + n) * 8];
      for (int o = 0; o < 8; ++o) {
        float bvv = 3.5e38f; int bii = 0x7fffffff; int bq = 0;
        {
          float v = mv[rb + 0*8 + p0]; int ii = mi[rb + 0*8 + p0];
          if (v < bvv || (v == bvv && ii < bii)) { bvv = v; bii = ii; bq = 0; }
        }
        {
          float v = mv[rb + 1*8 + p1]; int ii = mi[rb + 1*8 + p1];
          if (v < bvv || (v == bvv && ii < bii)) { bvv = v; bii = ii; bq = 1; }
        }
        {
          float v = mv[rb + 2*8 + p2]; int ii = mi[rb + 2*8 + p2];
          if (v < bvv || (v == bvv && ii < bii)) { bvv = v; bii = ii; bq = 2; }
        }
        {
          float v = mv[rb + 3*8 + p3]; int ii = mi[rb + 3*8 + p3];
          if (v < bvv || (v == bvv && ii < bii)) { bvv = v; bii = ii; bq = 3; }
        }
        p0 += (bq == 0); p1 += (bq == 1); p2 += (bq == 2); p3 += (bq == 3);
        op[o] = bii;
      }
    }
  }
}

// ---------------------------------------------------------------------------
// GKAN: g = hs + hw + (1/deg)*sum_nbr hw + bias, then rational activation.
// Wave per token, lane per channel.
// ---------------------------------------------------------------------------
__global__ __launch_bounds__(256) void gkan_kernel(
    const float* __restrict__ hs, const float* __restrict__ hw,
    const int* __restrict__ nbr, const float* __restrict__ bias,
    const float* __restrict__ kan_a, const float* __restrict__ kan_b,
    float* __restrict__ gpre)
{
  int row = blockIdx.x * 4 + (threadIdx.x >> 6);
  int d = threadIdx.x & 63;
  float degf = 8.0f + 1e-6f;
  float coef = 1.0f / degf;   // dinv_n * dinv_m, all degrees equal
  size_t bbase = (size_t)(row / 729) * 729;
  float v = hs[(size_t)row * 64 + d] + hw[(size_t)row * 64 + d] + bias[d];
  float nsum = 0.f;
  #pragma unroll
  for (int j = 0; j < 8; ++j) {
    int m = nbr[(size_t)row * 8 + j];
    nsum += hw[(bbase + m) * 64 + d];
  }
  v += coef * nsum;
  float a0 = kan_a[d*3], a1 = kan_a[d*3+1], a2 = kan_a[d*3+2];
  float b0 = kan_b[d*2], b1 = kan_b[d*2+1];
  float v2 = v * v;
  float num = a0 + a1*v + a2*v2;
  float den = 1.f + fabsf(b0*v + b1*v2);
  gpre[(size_t)row * 64 + d] = num / (den + 1e-8f);
}

// BN stats over (B,N) per channel d (layout [rows][64]) via double atomics.
__global__ __launch_bounds__(256) void stats_tok(
    const float* __restrict__ g, double* __restrict__ stats)
{
  int d = threadIdx.x & 63, qq = threadIdx.x >> 6;
  int r0 = blockIdx.x * 183;
  int rend = r0 + 183; if (rend > NROWS) rend = NROWS;
  float sm = 0.f, sq = 0.f;
  for (int r = r0 + qq; r < rend; r += 4) {
    float v = g[(size_t)r * 64 + d];
    sm += v; sq += v * v;
  }
  __shared__ float ls[256], lq[256];
  ls[threadIdx.x] = sm; lq[threadIdx.x] = sq;
  __syncthreads();
  if (threadIdx.x < 64) {
    sm = ls[d] + ls[64+d] + ls[128+d] + ls[192+d];
    sq = lq[d] + lq[64+d] + lq[128+d] + lq[192+d];
    atomicAdd(&stats[d], (double)sm);
    atomicAdd(&stats[64 + d], (double)sq);
  }
}

// ---------------------------------------------------------------------------
// Fuzzy attention: gn = BN(gpre); rbf; a1 = relu(W1 rbf); attn = sigmoid(W2 a1);
// out = gn*(1+attn). Wave per token.
// ---------------------------------------------------------------------------
__global__ __launch_bounds__(256) void fuzzy_attn(
    const float* __restrict__ gpre, const float* __restrict__ scshG,
    const float* __restrict__ centers, const float* __restrict__ gam,
    const float* __restrict__ w1, const float* __restrict__ b1,
    const float* __restrict__ w2, const float* __restrict__ b2,
    float* __restrict__ g2)
{
  int wv = threadIdx.x >> 6, d = threadIdx.x & 63;
  int row = blockIdx.x * 4 + wv;
  __shared__ float s_rbf[4][64];
  __shared__ float s_a1[4][16];
  float v = gpre[(size_t)row * 64 + d];
  float gn = fmaf(v, scshG[d], scshG[64 + d]);
  float acc = 0.f;
  #pragma unroll
  for (int f = 0; f < 9; ++f) {
    float dc = gn - centers[d*9 + f];
    acc += expf(-fabsf(gam[d*9 + f]) * dc * dc);
  }
  s_rbf[wv][d] = acc + 9e-10f;
  __syncthreads();
  if (d < 16) {
    float a = b1[d];
    #pragma unroll 8
    for (int k = 0; k < 64; ++k) a += w1[d*64 + k] * s_rbf[wv][k];
    s_a1[wv][d] = fmaxf(a, 0.f);
  }
  __syncthreads();
  float a2 = b2[d];
  #pragma unroll
  for (int i = 0; i < 16; ++i) a2 += w2[d*16 + i] * s_a1[wv][i];
  float sig = 1.f / (1.f + expf(-a2));
  g2[(size_t)row * 64 + d] = gn * (1.f + sig);
}

// pool: p[b,d] = 0.5*mean_n BN(g2) + 0.5*max_n BN(g2). Block per b.
__global__ __launch_bounds__(256) void pool_kernel(
    const float* __restrict__ g2, const float* __restrict__ scshF, float* __restrict__ p)
{
  int b = blockIdx.x;
  int d = threadIdx.x & 63, qq = threadIdx.x >> 6;
  float sc = scshF[d], sh = scshF[64 + d];
  float sm = 0.f, mx = -3.0e38f;
  for (int n = qq; n < 729; n += 4) {
    float v = fmaf(g2[((size_t)b * 729 + n) * 64 + d], sc, sh);
    sm += v; mx = fmaxf(mx, v);
  }
  __shared__ float ls[256], lm[256];
  ls[threadIdx.x] = sm; lm[threadIdx.x] = mx;
  __syncthreads();
  if (threadIdx.x < 64) {
    sm = ls[d] + ls[64+d] + ls[128+d] + ls[192+d];
    mx = fmaxf(fmaxf(lm[d], lm[64+d]), fmaxf(lm[128+d], lm[192+d]));
    p[b * 64 + d] = 0.5f * (sm / 729.f) + 0.5f * mx;
  }
}

// classifier: c = p@fc1^T+b; BN over batch; relu; out = c@fc2^T+b. One block.
__global__ __launch_bounds__(256) void classifier(
    const float* __restrict__ p, const float* __restrict__ f1w, const float* __restrict__ f1b,
    const float* __restrict__ bng, const float* __restrict__ bnb,
    const float* __restrict__ f2w, const float* __restrict__ f2b, float* __restrict__ outp)
{
  __shared__ float s_p[64 * 64];
  __shared__ float s_c[64 * 128];
  __shared__ float s_sc[128], s_sh[128];
  for (int i = threadIdx.x; i < 4096; i += 256) s_p[i] = p[i];
  __syncthreads();
  for (int o = threadIdx.x; o < 8192; o += 256) {
    int b = o >> 7, h = o & 127;
    float acc = f1b[h];
    #pragma unroll 8
    for (int d = 0; d < 64; ++d) acc += s_p[b*64 + d] * f1w[h*64 + d];
    s_c[o] = acc;
  }
  __syncthreads();
  if (threadIdx.x < 128) {
    int h = threadIdx.x;
    float sm = 0.f, sq = 0.f;
    for (int b = 0; b < 64; ++b) { float v = s_c[b*128 + h]; sm += v; sq += v*v; }
    float mu = sm / 64.f;
    float var = sq / 64.f - mu * mu;
    float rstd = rsqrtf(var + 1e-5f);
    float sc = bng[h] * rstd;
    s_sc[h] = sc; s_sh[h] = bnb[h] - mu * sc;
  }
  __syncthreads();
  for (int o = threadIdx.x; o < 1024; o += 256) {
    int b = o >> 4, j = o & 15;
    float acc = f2b[j];
    #pragma unroll 8
    for (int h = 0; h < 128; ++h) {
      float v = fmaxf(fmaf(s_c[b*128 + h], s_sc[h], s_sh[h]), 0.f);
      acc += f2w[j*128 + h] * v;
    }
    outp[o] = acc;
  }
}

// ---------------------------------------------------------------------------
extern "C" void kernel_launch(void* const* d_in, const int* in_sizes, int n_in,
                              void* d_out, int out_size, void* d_ws, size_t ws_size,
                              hipStream_t stream)
{
  const float* x      = (const float*)d_in[0];
  const float* c1w    = (const float*)d_in[1];
  const float* c1b    = (const float*)d_in[2];
  const float* bn1g   = (const float*)d_in[3];
  const float* bn1b   = (const float*)d_in[4];
  const float* c2wt   = (const float*)d_in[5];
  const float* c2b    = (const float*)d_in[6];
  const float* bn2g   = (const float*)d_in[7];
  const float* bn2b   = (const float*)d_in[8];
  const float* c3wt   = (const float*)d_in[9];
  const float* c3b    = (const float*)d_in[10];
  const float* bn3g   = (const float*)d_in[11];
  const float* bn3b   = (const float*)d_in[12];
  const float* wself  = (const float*)d_in[13];
  const float* wnb    = (const float*)d_in[14];
  const float* gbias  = (const float*)d_in[15];
  const float* kana   = (const float*)d_in[16];
  const float* kanb   = (const float*)d_in[17];
  const float* gbng   = (const float*)d_in[18];
  const float* gbnb   = (const float*)d_in[19];
  const float* cent   = (const float*)d_in[20];
  const float* gamr   = (const float*)d_in[21];
  const float* aw1    = (const float*)d_in[22];
  const float* ab1    = (const float*)d_in[23];
  const float* aw2    = (const float*)d_in[24];
  const float* ab2    = (const float*)d_in[25];
  const float* fbng   = (const float*)d_in[26];
  const float* fbnb   = (const float*)d_in[27];
  const float* f1w    = (const float*)d_in[28];
  const float* f1b    = (const float*)d_in[29];
  const float* cbng   = (const float*)d_in[30];
  const float* cbnb   = (const float*)d_in[31];
  const float* f2w    = (const float*)d_in[32];
  const float* f2b    = (const float*)d_in[33];

  char* ws = (char*)d_ws;
  float*  P     = (float*) (ws + 0);          // 11,943,936 B: conv partials
  float*  c1    = (float*) (ws + 11943936);   //  5,971,968 B
  float*  c2    = (float*) (ws + 17915904);   // 11,943,936 B
  float*  c3    = (float*) (ws + 29859840);   // 11,943,936 B
  float*  t     = (float*) (ws + 41803776);   // 11,943,936 B
  int*    nbr   = (int*)   (ws + 53747712);   //  1,492,992 B
  float*  xx    = (float*) (ws + 55240704);   //    186,624 B
  double* stats = (double*)(ws + 55427328);   //      4,608 B (576 doubles)
  float*  scsh  = (float*) (ws + 55431936);   //      2,304 B (576 floats)
  float*  pbuf  = (float*) (ws + 55434240);   //     16,384 B
  // aliases (lifetimes are disjoint on the serialized stream):
  float* hs   = c2;   // written after conv3 consumed c2
  float* hw   = P;    // written after reduce3 consumed P
  float* gpre = c3;   // written after transpose consumed c3
  float* g2   = t;    // written after gemm+dist consumed t

  hipMemsetAsync(stats, 0, 576 * sizeof(double), stream);

  const float inv = 1.0f / 46656.0f;

  // conv1 (2 cin slabs) -> reduce+stats -> finalize
  conv3x3_slab<8,8><<<dim3(512), dim3(256), 0, stream>>>(x,  c1w, nullptr,  P, 200, 32, 100, 2);
  conv_reduce_stats<<<dim3(2048), dim3(256), 0, stream>>>(P, c1b, c1, stats,       32, 2);
  bn_finalize<<<dim3(1), dim3(32), 0, stream>>>(stats,       bn1g, bn1b, scsh,       32, inv);
  // conv2
  conv3x3_slab<8,8><<<dim3(512), dim3(256), 0, stream>>>(c1, c2wt, scsh,     P,  32, 64,  32, 1);
  conv_reduce_stats<<<dim3(4096), dim3(256), 0, stream>>>(P, c2b, c2, stats + 64,  64, 1);
  bn_finalize<<<dim3(1), dim3(64), 0, stream>>>(stats + 64,  bn2g, bn2b, scsh + 64,  64, inv);
  // conv3
  conv3x3_slab<8,8><<<dim3(512), dim3(256), 0, stream>>>(c2, c3wt, scsh + 64, P, 64, 64,  64, 1);
  conv_reduce_stats<<<dim3(4096), dim3(256), 0, stream>>>(P, c3b, c3, stats + 192, 64, 1);
  bn_finalize<<<dim3(1), dim3(64), 0, stream>>>(stats + 192, bn3g, bn3b, scsh + 192, 64, inv);
  // tokens
  bn_transpose_xx<<<dim3(768), dim3(256), 0, stream>>>(c3, scsh + 192, t, xx);
  gemm_selfnb<<<dim3(768), dim3(256), 0, stream>>>(t, wself, wnb, hs, hw);
  dist_topk<<<dim3(768), dim3(256), 0, stream>>>(t, xx, nbr);
  gkan_kernel<<<dim3(11664), dim3(256), 0, stream>>>(hs, hw, nbr, gbias, kana, kanb, gpre);
  stats_tok<<<dim3(256), dim3(256), 0, stream>>>(gpre, stats + 320);
  bn_finalize<<<dim3(1), dim3(64), 0, stream>>>(stats + 320, gbng, gbnb, scsh + 320, 64, inv);
  fuzzy_attn<<<dim3(11664), dim3(256), 0, stream>>>(gpre, scsh + 320, cent, gamr, aw1, ab1, aw2, ab2, g2);
  stats_tok<<<dim3(256), dim3(256), 0, stream>>>(g2, stats + 448);
  bn_finalize<<<dim3(1), dim3(64), 0, stream>>>(stats + 448, fbng, fbnb, scsh + 448, 64, inv);
  pool_kernel<<<dim3(64), dim3(256), 0, stream>>>(g2, scsh + 448, pbuf);
  classifier<<<dim3(1), dim3(256), 0, stream>>>(pbuf, f1w, f1b, cbng, cbnb, f2w, f2b, (float*)d_out);
}